// Round 6
// baseline (805.742 us; speedup 1.0000x reference)
//
#include <hip/hip_runtime.h>

#define NN 8192
#define FF 256
#define PST 136   // P LDS row stride in halves (128 + 8 pad, 16B-aligned)

typedef _Float16 h8 __attribute__((ext_vector_type(8)));
typedef _Float16 h4 __attribute__((ext_vector_type(4)));
typedef float    f4 __attribute__((ext_vector_type(4)));
typedef int      i4v __attribute__((ext_vector_type(4)));

// monotone float<->uint encoding for atomicMax on fp32
__device__ __forceinline__ unsigned fenc(float x) {
  unsigned u = __float_as_uint(x);
  return (u & 0x80000000u) ? ~u : (u | 0x80000000u);
}
__device__ __forceinline__ float fdec(unsigned e) {
  unsigned u = (e & 0x80000000u) ? (e ^ 0x80000000u) : ~e;
  return __uint_as_float(u);
}

// lgkm-only barrier (CK block_sync_lds pattern): publishes LDS writes without
// draining vmem (plain __syncthreads emits s_waitcnt vmcnt(0) -> kills the
// adj prefetch pipeline).
__device__ __forceinline__ void sync_lds() {
  __builtin_amdgcn_s_waitcnt(0xc07f);   // lgkmcnt(0), vmcnt/expcnt ignored
  __builtin_amdgcn_s_barrier();
}

// ---------------- Kernel 1: Wh = h@W (fp32 vector), s1, s2(f16), wfrag -------
// grid 512 x 256 thr. Block = 16 rows of h = half of k-tile (blockIdx>>1).
// wfrag[(kt*16+n)*512 + lane*8 + j] = Wh[kt*32 + (lane>>4)*8 + j][n*16 + (lane&15)]
// R4 fix: s2max via per-block LDS reduction + ONE atomicMax per block
// (was 8192 single-address device atomics -> ~90 us serialization tail).
__global__ __launch_bounds__(256) void k_wh(
    const float* __restrict__ h, const float* __restrict__ W,
    const float* __restrict__ a, _Float16* __restrict__ wfrag,
    float* __restrict__ s1, _Float16* __restrict__ s2h,
    unsigned* __restrict__ s2maxe) {
  __shared__ float hs[16 * 256];        // 16 KB
  __shared__ _Float16 whs[16 * 264];    // 8.25 KB
  __shared__ unsigned bm[4];            // per-wave p2-max (fenc domain)
  const int t = threadIdx.x;
  const int r0 = blockIdx.x * 16;
#pragma unroll
  for (int i = 0; i < 4; ++i) {
    int idx = i * 1024 + t * 4;
    *(f4*)&hs[idx] = *(const f4*)&h[(size_t)r0 * 256 + idx];
  }
  __syncthreads();
  const int lane = t & 63;
  const int wv = t >> 6;        // 0..3
  const int rg = wv * 4;
  const int c4 = lane * 4;
  float acc[4][4];
#pragma unroll
  for (int i = 0; i < 4; ++i)
#pragma unroll
    for (int k = 0; k < 4; ++k) acc[i][k] = 0.f;
  f4 w[8];
#pragma unroll
  for (int i = 0; i < 8; ++i) w[i] = *(const f4*)&W[i * 256 + c4];
  for (int f = 0; f < 256; f += 8) {
    f4 nw[8];
    if (f < 248) {
#pragma unroll
      for (int i = 0; i < 8; ++i) nw[i] = *(const f4*)&W[(f + 8 + i) * 256 + c4];
    }
#pragma unroll
    for (int i = 0; i < 4; ++i) {
      f4 h0 = *(const f4*)&hs[(rg + i) * 256 + f];
      f4 h1 = *(const f4*)&hs[(rg + i) * 256 + f + 4];
#pragma unroll
      for (int k = 0; k < 4; ++k)
        acc[i][k] += h0[0]*w[0][k] + h0[1]*w[1][k] + h0[2]*w[2][k] + h0[3]*w[3][k]
                   + h1[0]*w[4][k] + h1[1]*w[5][k] + h1[2]*w[6][k] + h1[3]*w[7][k];
    }
    if (f < 248) {
#pragma unroll
      for (int i = 0; i < 8; ++i) w[i] = nw[i];
    }
  }
  float a1v[4], a2v[4];
#pragma unroll
  for (int k = 0; k < 4; ++k) { a1v[k] = a[c4 + k]; a2v[k] = a[256 + c4 + k]; }
  unsigned wmax = 0u;   // fenc domain: 0 < fenc(x) for all finite x
#pragma unroll
  for (int i = 0; i < 4; ++i) {
    h4 hh;
    float p1 = 0.f, p2 = 0.f;
#pragma unroll
    for (int k = 0; k < 4; ++k) {
      hh[k] = (_Float16)acc[i][k];
      p1 += acc[i][k] * a1v[k];
      p2 += acc[i][k] * a2v[k];
    }
    *(h4*)&whs[(rg + i) * 264 + c4] = hh;
#pragma unroll
    for (int off = 32; off; off >>= 1) {
      p1 += __shfl_xor(p1, off);
      p2 += __shfl_xor(p2, off);
    }
    if (lane == 0) {
      const int r = r0 + rg + i;
      s1[r] = p1;
      s2h[r] = (_Float16)p2;
      const unsigned e = fenc(p2);
      wmax = (e > wmax) ? e : wmax;
    }
  }
  if (lane == 0) bm[wv] = wmax;
  __syncthreads();
  if (t == 0) {
    unsigned m01 = (bm[0] > bm[1]) ? bm[0] : bm[1];
    unsigned m23 = (bm[2] > bm[3]) ? bm[2] : bm[3];
    atomicMax(s2maxe, (m01 > m23) ? m01 : m23);   // 1 atomic per block (512 total)
  }
  {
    const int kt = blockIdx.x >> 1;
    const int hb = blockIdx.x & 1;
    const int lp = hb * 32 + (t & 31);
    const int kb = ((t & 31) >> 4) * 8;
    const int m16e = t & 15;
#pragma unroll
    for (int p = 0; p < 2; ++p) {
      const int n = (t >> 5) + p * 8;
      h8 v;
#pragma unroll
      for (int j = 0; j < 8; ++j) v[j] = whs[(kb + j) * 264 + n * 16 + m16e];
      *(h8*)&wfrag[(((size_t)kt * 16 + n) << 9) + lp * 8] = v;
    }
  }
}

// ---------------- Kernel 2: fused attention ----------------------------------
// grid 512 = (rt 0..127) x (kq 0..3); 512 thr.
// R5: LB(512,8) -> 4 blocks/CU (was 2). VGPR_Count is already exactly 64 and
// LDS 4x38.9KB = 155.6KB < 160KB, so the cap was the only occupancy limiter.
// k_gat is latency-bound (hbm 32%, VALU 35%, Mfma 20%, occ 37% - R4 probe);
// doubling resident blocks hides the adj HBM latency + per-period barrier.
// Block: 64 rows x 256 cols x 2048 k. Period = 128 k (16 periods).
__global__ __launch_bounds__(512, 8) void k_gat(
    const int* __restrict__ adj, const _Float16* __restrict__ wfrag,
    const float* __restrict__ s1g, const _Float16* __restrict__ s2h,
    const unsigned* __restrict__ s2maxe,
    float* __restrict__ o0, float* __restrict__ o1,
    float* __restrict__ o2, float* __restrict__ o3,
    float* __restrict__ lbuf) {
  __shared__ _Float16 P[2][64 * PST];   // 34 KB
  __shared__ _Float16 s2l[2048];        // 4 KB
  const int t = threadIdx.x;
  const int lane = t & 63;
  const int w = t >> 6;          // 0..7: score rows {8w+q, 8w+q+4}; cols [32w,32w+32)
  const int q = lane >> 4;       // 0..3
  const int m16 = lane & 15;
  const int rt = (int)blockIdx.x >> 2;
  const int kq = (int)blockIdx.x & 3;
  const int r0 = rt * 64;

  if (t < 256) ((h8*)s2l)[t] = ((const h8*)(s2h + kq * 2048))[t];  // kq-quarter s2

  const int srA = 8 * w + q;                 // lane's two score rows (local)
  const int srB = srA + 4;
  const float s2m = fdec(*s2maxe);
  const float s1A = s1g[r0 + srA];
  const float s1B = s1g[r0 + srB];
  const float uA0 = s1A + s2m, uB0 = s1B + s2m;
  const float miA = fmaxf(uA0, 0.2f * uA0);  // >= leaky(s1+s2[j]) for all j
  const float miB = fmaxf(uB0, 0.2f * uB0);
  const float sAmi = s1A - miA, sBmi = s1B - miB;

  f4 acc[4][2];
#pragma unroll
  for (int m = 0; m < 4; ++m)
#pragma unroll
    for (int n = 0; n < 2; ++n)
#pragma unroll
      for (int e = 0; e < 4; ++e) acc[m][n][e] = 0.f;
  float lsA = 0.f, lsB = 0.f;

  const int* adjA = adj + (size_t)(r0 + srA) * NN + kq * 2048 + m16 * 8;
  const int* adjB = adj + (size_t)(r0 + srB) * NN + kq * 2048 + m16 * 8;
  __syncthreads();   // s2l ready (once; full drain harmless here)

  // preload adj for period 0
  i4v a0 = *(const i4v*)(adjA);
  i4v a1 = *(const i4v*)(adjA + 4);
  i4v b0 = *(const i4v*)(adjB);
  i4v b1 = *(const i4v*)(adjB + 4);

  for (int p = 0; p < 16; ++p) {
    // (1) B-frags for this period: 4 k-subtiles x 2 n-tiles, coalesced L2 loads
    const _Float16* wfb =
        wfrag + ((((size_t)(kq * 64 + p * 4)) * 16 + 2 * w) << 9) + lane * 8;
    h8 bb[8];
#pragma unroll
    for (int ks = 0; ks < 4; ++ks) {
      bb[2 * ks]     = *(const h8*)(wfb + ks * 8192);
      bb[2 * ks + 1] = *(const h8*)(wfb + ks * 8192 + 512);
    }
    // (2) adj prefetch for p+1 (HBM; consumed next period)
    i4v na0 = a0, na1 = a1, nb0 = b0, nb1 = b1;
    if (p < 15) {
      na0 = *(const i4v*)(adjA + (p + 1) * 128);
      na1 = *(const i4v*)(adjA + (p + 1) * 128 + 4);
      nb0 = *(const i4v*)(adjB + (p + 1) * 128);
      nb1 = *(const i4v*)(adjB + (p + 1) * 128 + 4);
    }
    // (3) scores for both rows: p = exp(leaky(s1+s2) - mi)
    const h8 s2c = *(const h8*)&s2l[p * 128 + m16 * 8];
    h8 pA, pB;
#pragma unroll
    for (int j = 0; j < 8; ++j) {
      const float s2v = (float)s2c[j];
      const int mA = (j < 4) ? a0[j] : a1[j - 4];
      const int mB = (j < 4) ? b0[j] : b1[j - 4];
      const float uA = s1A + s2v;
      const float uB = s1B + s2v;
      const float argA = sAmi + s2v - 0.8f * fminf(uA, 0.f);
      const float argB = sBmi + s2v - 0.8f * fminf(uB, 0.f);
      const float pvA = (mA > 0) ? __expf(argA) : 0.f;
      const float pvB = (mB > 0) ? __expf(argB) : 0.f;
      lsA += pvA; pA[j] = (_Float16)pvA;
      lsB += pvB; pB[j] = (_Float16)pvB;
    }
    _Float16* Pb = &P[p & 1][0];
    *(h8*)&Pb[srA * PST + m16 * 8] = pA;
    *(h8*)&Pb[srB * PST + m16 * 8] = pB;
    // (4) publish P without draining vmem
    sync_lds();
    // (5) MFMA: A from LDS (4 m-tiles), B from regs (issued at (1))
#pragma unroll
    for (int ks = 0; ks < 4; ++ks) {
      const h8 A0 = *(const h8*)&Pb[(     m16) * PST + ks * 32 + q * 8];
      const h8 A1 = *(const h8*)&Pb[(16 + m16) * PST + ks * 32 + q * 8];
      const h8 A2 = *(const h8*)&Pb[(32 + m16) * PST + ks * 32 + q * 8];
      const h8 A3 = *(const h8*)&Pb[(48 + m16) * PST + ks * 32 + q * 8];
      acc[0][0] = __builtin_amdgcn_mfma_f32_16x16x32_f16(A0, bb[2*ks],   acc[0][0], 0, 0, 0);
      acc[0][1] = __builtin_amdgcn_mfma_f32_16x16x32_f16(A0, bb[2*ks+1], acc[0][1], 0, 0, 0);
      acc[1][0] = __builtin_amdgcn_mfma_f32_16x16x32_f16(A1, bb[2*ks],   acc[1][0], 0, 0, 0);
      acc[1][1] = __builtin_amdgcn_mfma_f32_16x16x32_f16(A1, bb[2*ks+1], acc[1][1], 0, 0, 0);
      acc[2][0] = __builtin_amdgcn_mfma_f32_16x16x32_f16(A2, bb[2*ks],   acc[2][0], 0, 0, 0);
      acc[2][1] = __builtin_amdgcn_mfma_f32_16x16x32_f16(A2, bb[2*ks+1], acc[2][1], 0, 0, 0);
      acc[3][0] = __builtin_amdgcn_mfma_f32_16x16x32_f16(A3, bb[2*ks],   acc[3][0], 0, 0, 0);
      acc[3][1] = __builtin_amdgcn_mfma_f32_16x16x32_f16(A3, bb[2*ks+1], acc[3][1], 0, 0, 0);
    }
    a0 = na0; a1 = na1; b0 = nb0; b1 = nb1;
  }

  // partial softmax denominators: reduce over the 16 m16 lanes
  lsA += __shfl_xor(lsA, 1);
  lsA += __shfl_xor(lsA, 2);
  lsA += __shfl_xor(lsA, 4);
  lsA += __shfl_xor(lsA, 8);
  lsB += __shfl_xor(lsB, 1);
  lsB += __shfl_xor(lsB, 2);
  lsB += __shfl_xor(lsB, 4);
  lsB += __shfl_xor(lsB, 8);
  if (m16 == 0) {
    lbuf[kq * NN + r0 + srA] = lsA;
    lbuf[kq * NN + r0 + srB] = lsB;
  }

  // partial O: plain stores (each element written once per kq)
  float* ob = (kq == 0) ? o0 : (kq == 1) ? o1 : (kq == 2) ? o2 : o3;
#pragma unroll
  for (int m = 0; m < 4; ++m)
#pragma unroll
    for (int n = 0; n < 2; ++n)
#pragma unroll
      for (int v = 0; v < 4; ++v)
        ob[(size_t)(r0 + m * 16 + q * 4 + v) * FF + w * 32 + n * 16 + m16] =
            acc[m][n][v];
}

// ---------------- Kernel 3: combine quarters, normalize, elu -----------------
__global__ __launch_bounds__(256) void k_fin(
    float* __restrict__ out, const float* __restrict__ o1,
    const float* __restrict__ o2, const float* __restrict__ o3,
    const float* __restrict__ lbuf) {
  const int t = threadIdx.x;
  const int row = blockIdx.x * 16 + (t >> 4);
  const int c0 = (t & 15) * 16;
  const float linv = 1.0f / (lbuf[row] + lbuf[NN + row] +
                             lbuf[2 * NN + row] + lbuf[3 * NN + row]);
#pragma unroll
  for (int i = 0; i < 4; ++i) {
    f4 v0 = *(const f4*)&out[(size_t)row * FF + c0 + i * 4];
    f4 v1 = *(const f4*)&o1[(size_t)row * FF + c0 + i * 4];
    f4 v2 = *(const f4*)&o2[(size_t)row * FF + c0 + i * 4];
    f4 v3 = *(const f4*)&o3[(size_t)row * FF + c0 + i * 4];
    f4 o;
#pragma unroll
    for (int e = 0; e < 4; ++e) {
      float x = (v0[e] + v1[e] + v2[e] + v3[e]) * linv;
      o[e] = (x > 0.f) ? x : (__expf(x) - 1.f);
    }
    *(f4*)&out[(size_t)row * FF + c0 + i * 4] = o;
  }
}

extern "C" void kernel_launch(void* const* d_in, const int* in_sizes, int n_in,
                              void* d_out, int out_size, void* d_ws, size_t ws_size,
                              hipStream_t stream) {
  const float* h   = (const float*)d_in[0];
  const int*   adj = (const int*)d_in[1];
  const float* W   = (const float*)d_in[2];
  const float* a   = (const float*)d_in[3];
  float* out = (float*)d_out;

  char* ws = (char*)d_ws;
  _Float16* wfrag = (_Float16*)ws;                                 // 4 MB
  float*    o1    = (float*)(ws + (4u << 20));                     // 8 MB (kq=1)
  float*    o2    = (float*)(ws + (12u << 20));                    // 8 MB (kq=2)
  float*    o3    = (float*)(ws + (20u << 20));                    // 8 MB (kq=3)
  float*    lbuf  = (float*)(ws + (28u << 20));                    // 128 KB (4 x 8192)
  unsigned* s2me  = (unsigned*)(ws + (28u << 20) + 131072);        // 4 B (+60 pad)
  float*    s1    = (float*)(ws + (28u << 20) + 131072 + 64);      // 32 KB
  _Float16* s2h   = (_Float16*)(ws + (28u << 20) + 131072 + 64 + 32768); // 16 KB

  hipMemsetAsync(s2me, 0, 4, stream);   // fenc-domain -inf
  k_wh<<<512, 256, 0, stream>>>(h, W, a, wfrag, s1, s2h, s2me);
  k_gat<<<512, 512, 0, stream>>>(adj, wfrag, s1, s2h, s2me, out, o1, o2, o3, lbuf);
  k_fin<<<512, 256, 0, stream>>>(out, o1, o2, o3, lbuf);
}

// Round 7
// 428.313 us; speedup vs baseline: 1.8812x; 1.8812x over previous
//
#include <hip/hip_runtime.h>

#define NN 8192
#define FF 256
#define PST 136   // P LDS row stride in halves (128 + 8 pad, 16B-aligned)

typedef _Float16 h8 __attribute__((ext_vector_type(8)));
typedef _Float16 h4 __attribute__((ext_vector_type(4)));
typedef float    f4 __attribute__((ext_vector_type(4)));
typedef int      i4v __attribute__((ext_vector_type(4)));

// monotone float<->uint encoding for atomicMax on fp32
__device__ __forceinline__ unsigned fenc(float x) {
  unsigned u = __float_as_uint(x);
  return (u & 0x80000000u) ? ~u : (u | 0x80000000u);
}
__device__ __forceinline__ float fdec(unsigned e) {
  unsigned u = (e & 0x80000000u) ? (e ^ 0x80000000u) : ~e;
  return __uint_as_float(u);
}

// lgkm-only barrier (CK block_sync_lds pattern): publishes LDS writes without
// draining vmem (plain __syncthreads emits s_waitcnt vmcnt(0) -> kills the
// adj prefetch pipeline).
__device__ __forceinline__ void sync_lds() {
  __builtin_amdgcn_s_waitcnt(0xc07f);   // lgkmcnt(0), vmcnt/expcnt ignored
  __builtin_amdgcn_s_barrier();
}

// ---------------- Kernel 1: Wh = h@W (fp32 vector), s1, s2(f16), wfrag -------
// grid 512 x 256 thr. Block = 16 rows of h = half of k-tile (blockIdx>>1).
// wfrag[(kt*16+n)*512 + lane*8 + j] = Wh[kt*32 + (lane>>4)*8 + j][n*16 + (lane&15)]
// R4 fix: s2max via per-block LDS reduction + ONE atomicMax per block
// (was 8192 single-address device atomics -> ~90 us serialization tail).
__global__ __launch_bounds__(256) void k_wh(
    const float* __restrict__ h, const float* __restrict__ W,
    const float* __restrict__ a, _Float16* __restrict__ wfrag,
    float* __restrict__ s1, _Float16* __restrict__ s2h,
    unsigned* __restrict__ s2maxe) {
  __shared__ float hs[16 * 256];        // 16 KB
  __shared__ _Float16 whs[16 * 264];    // 8.25 KB
  __shared__ unsigned bm[4];            // per-wave p2-max (fenc domain)
  const int t = threadIdx.x;
  const int r0 = blockIdx.x * 16;
#pragma unroll
  for (int i = 0; i < 4; ++i) {
    int idx = i * 1024 + t * 4;
    *(f4*)&hs[idx] = *(const f4*)&h[(size_t)r0 * 256 + idx];
  }
  __syncthreads();
  const int lane = t & 63;
  const int wv = t >> 6;        // 0..3
  const int rg = wv * 4;
  const int c4 = lane * 4;
  float acc[4][4];
#pragma unroll
  for (int i = 0; i < 4; ++i)
#pragma unroll
    for (int k = 0; k < 4; ++k) acc[i][k] = 0.f;
  f4 w[8];
#pragma unroll
  for (int i = 0; i < 8; ++i) w[i] = *(const f4*)&W[i * 256 + c4];
  for (int f = 0; f < 256; f += 8) {
    f4 nw[8];
    if (f < 248) {
#pragma unroll
      for (int i = 0; i < 8; ++i) nw[i] = *(const f4*)&W[(f + 8 + i) * 256 + c4];
    }
#pragma unroll
    for (int i = 0; i < 4; ++i) {
      f4 h0 = *(const f4*)&hs[(rg + i) * 256 + f];
      f4 h1 = *(const f4*)&hs[(rg + i) * 256 + f + 4];
#pragma unroll
      for (int k = 0; k < 4; ++k)
        acc[i][k] += h0[0]*w[0][k] + h0[1]*w[1][k] + h0[2]*w[2][k] + h0[3]*w[3][k]
                   + h1[0]*w[4][k] + h1[1]*w[5][k] + h1[2]*w[6][k] + h1[3]*w[7][k];
    }
    if (f < 248) {
#pragma unroll
      for (int i = 0; i < 8; ++i) w[i] = nw[i];
    }
  }
  float a1v[4], a2v[4];
#pragma unroll
  for (int k = 0; k < 4; ++k) { a1v[k] = a[c4 + k]; a2v[k] = a[256 + c4 + k]; }
  unsigned wmax = 0u;   // fenc domain: 0 < fenc(x) for all finite x
#pragma unroll
  for (int i = 0; i < 4; ++i) {
    h4 hh;
    float p1 = 0.f, p2 = 0.f;
#pragma unroll
    for (int k = 0; k < 4; ++k) {
      hh[k] = (_Float16)acc[i][k];
      p1 += acc[i][k] * a1v[k];
      p2 += acc[i][k] * a2v[k];
    }
    *(h4*)&whs[(rg + i) * 264 + c4] = hh;
#pragma unroll
    for (int off = 32; off; off >>= 1) {
      p1 += __shfl_xor(p1, off);
      p2 += __shfl_xor(p2, off);
    }
    if (lane == 0) {
      const int r = r0 + rg + i;
      s1[r] = p1;
      s2h[r] = (_Float16)p2;
      const unsigned e = fenc(p2);
      wmax = (e > wmax) ? e : wmax;
    }
  }
  if (lane == 0) bm[wv] = wmax;
  __syncthreads();
  if (t == 0) {
    unsigned m01 = (bm[0] > bm[1]) ? bm[0] : bm[1];
    unsigned m23 = (bm[2] > bm[3]) ? bm[2] : bm[3];
    atomicMax(s2maxe, (m01 > m23) ? m01 : m23);   // 1 atomic per block (512 total)
  }
  {
    const int kt = blockIdx.x >> 1;
    const int hb = blockIdx.x & 1;
    const int lp = hb * 32 + (t & 31);
    const int kb = ((t & 31) >> 4) * 8;
    const int m16e = t & 15;
#pragma unroll
    for (int p = 0; p < 2; ++p) {
      const int n = (t >> 5) + p * 8;
      h8 v;
#pragma unroll
      for (int j = 0; j < 8; ++j) v[j] = whs[(kb + j) * 264 + n * 16 + m16e];
      *(h8*)&wfrag[(((size_t)kt * 16 + n) << 9) + lp * 8] = v;
    }
  }
}

// ---------------- Kernel 2: fused attention ----------------------------------
// R6: grid 1024 = (rt 0..255) x (kq 0..3); 512 thr; LB(512,4) [R6 lesson: the
// LB 2nd arg is a REGALLOC budget, not an occupancy hint -- (512,8) forced a
// 64-reg unified budget and spilled to scratch, 5x slower].
// Block: 32 rows x 256 cols x 2048 k, 16 periods. Grid was the occupancy
// limiter (512 blocks / 256 CUs = 2 blocks/CU of WORK); 1024 blocks -> 4/CU.
// LDS 21.4 KB (7 blocks) and VGPR ~<=64 (acc halved vs R5) both admit 4.
__global__ __launch_bounds__(512, 4) void k_gat(
    const int* __restrict__ adj, const _Float16* __restrict__ wfrag,
    const float* __restrict__ s1g, const _Float16* __restrict__ s2h,
    const unsigned* __restrict__ s2maxe,
    float* __restrict__ o0, float* __restrict__ o1,
    float* __restrict__ o2, float* __restrict__ o3,
    float* __restrict__ lbuf) {
  __shared__ _Float16 P[2][32 * PST];   // 17.4 KB
  __shared__ _Float16 s2l[2048];        // 4 KB
  const int t = threadIdx.x;
  const int lane = t & 63;
  const int w = t >> 6;          // 0..7: score rows 4w+q; cols [32w,32w+32)
  const int q = lane >> 4;       // 0..3
  const int m16 = lane & 15;
  const int rt = (int)blockIdx.x >> 2;
  const int kq = (int)blockIdx.x & 3;
  const int r0 = rt * 32;

  if (t < 256) ((h8*)s2l)[t] = ((const h8*)(s2h + kq * 2048))[t];  // kq-quarter s2

  const int srow = 4 * w + q;                // this lane's score row (local)
  const float s2m = fdec(*s2maxe);
  const float s1r = s1g[r0 + srow];
  const float u0 = s1r + s2m;
  const float mi = fmaxf(u0, 0.2f * u0);     // >= leaky(s1r+s2[j]) for all j
  const float s1mi = s1r - mi;

  f4 acc[2][2];
#pragma unroll
  for (int m = 0; m < 2; ++m)
#pragma unroll
    for (int n = 0; n < 2; ++n)
#pragma unroll
      for (int e = 0; e < 4; ++e) acc[m][n][e] = 0.f;
  float lsum = 0.f;

  const int* adjp = adj + (size_t)(r0 + srow) * NN + kq * 2048 + m16 * 8;
  __syncthreads();   // s2l ready (once; full drain harmless here)

  // preload adj for period 0
  i4v c0 = *(const i4v*)(adjp);
  i4v c1 = *(const i4v*)(adjp + 4);

  for (int p = 0; p < 16; ++p) {
    // (1) B-frags for this period: 4 k-subtiles x 2 n-tiles, coalesced L2 loads
    const _Float16* wfb =
        wfrag + ((((size_t)(kq * 64 + p * 4)) * 16 + 2 * w) << 9) + lane * 8;
    h8 bb[8];
#pragma unroll
    for (int ks = 0; ks < 4; ++ks) {
      bb[2 * ks]     = *(const h8*)(wfb + ks * 8192);
      bb[2 * ks + 1] = *(const h8*)(wfb + ks * 8192 + 512);
    }
    // (2) adj prefetch for p+1 (HBM; consumed next period)
    i4v n0 = c0, n1 = c1;
    if (p < 15) {
      n0 = *(const i4v*)(adjp + (p + 1) * 128);
      n1 = *(const i4v*)(adjp + (p + 1) * 128 + 4);
    }
    // (3) scores: p = exp(leaky(s1+s2) - mi); leaky(u) = u - 0.8*min(u,0)
    const h8 s2c = *(const h8*)&s2l[p * 128 + m16 * 8];
    h8 pa;
#pragma unroll
    for (int j = 0; j < 8; ++j) {
      const float s2v = (float)s2c[j];
      const float u = s1r + s2v;
      const float arg = s1mi + s2v - 0.8f * fminf(u, 0.f);
      const int msk = (j < 4) ? c0[j] : c1[j - 4];
      const float pv = (msk > 0) ? __expf(arg) : 0.f;
      lsum += pv;
      pa[j] = (_Float16)pv;
    }
    _Float16* Pb = &P[p & 1][0];
    *(h8*)&Pb[srow * PST + m16 * 8] = pa;
    // (4) publish P without draining vmem
    sync_lds();
    // (5) MFMA: A from LDS (2 m-tiles), B from regs (issued at (1))
#pragma unroll
    for (int ks = 0; ks < 4; ++ks) {
      const h8 A0 = *(const h8*)&Pb[(     m16) * PST + ks * 32 + q * 8];
      const h8 A1 = *(const h8*)&Pb[(16 + m16) * PST + ks * 32 + q * 8];
      acc[0][0] = __builtin_amdgcn_mfma_f32_16x16x32_f16(A0, bb[2*ks],   acc[0][0], 0, 0, 0);
      acc[0][1] = __builtin_amdgcn_mfma_f32_16x16x32_f16(A0, bb[2*ks+1], acc[0][1], 0, 0, 0);
      acc[1][0] = __builtin_amdgcn_mfma_f32_16x16x32_f16(A1, bb[2*ks],   acc[1][0], 0, 0, 0);
      acc[1][1] = __builtin_amdgcn_mfma_f32_16x16x32_f16(A1, bb[2*ks+1], acc[1][1], 0, 0, 0);
    }
    c0 = n0; c1 = n1;
  }

  // partial softmax denominator (row srow): reduce over the 16 m16 lanes
  lsum += __shfl_xor(lsum, 1);
  lsum += __shfl_xor(lsum, 2);
  lsum += __shfl_xor(lsum, 4);
  lsum += __shfl_xor(lsum, 8);
  if (m16 == 0) lbuf[kq * NN + r0 + srow] = lsum;

  // partial O: plain stores (each element written once per kq)
  float* ob = (kq == 0) ? o0 : (kq == 1) ? o1 : (kq == 2) ? o2 : o3;
#pragma unroll
  for (int m = 0; m < 2; ++m)
#pragma unroll
    for (int n = 0; n < 2; ++n)
#pragma unroll
      for (int v = 0; v < 4; ++v)
        ob[(size_t)(r0 + m * 16 + q * 4 + v) * FF + w * 32 + n * 16 + m16] =
            acc[m][n][v];
}

// ---------------- Kernel 3: combine quarters, normalize, elu -----------------
__global__ __launch_bounds__(256) void k_fin(
    float* __restrict__ out, const float* __restrict__ o1,
    const float* __restrict__ o2, const float* __restrict__ o3,
    const float* __restrict__ lbuf) {
  const int t = threadIdx.x;
  const int row = blockIdx.x * 16 + (t >> 4);
  const int c0 = (t & 15) * 16;
  const float linv = 1.0f / (lbuf[row] + lbuf[NN + row] +
                             lbuf[2 * NN + row] + lbuf[3 * NN + row]);
#pragma unroll
  for (int i = 0; i < 4; ++i) {
    f4 v0 = *(const f4*)&out[(size_t)row * FF + c0 + i * 4];
    f4 v1 = *(const f4*)&o1[(size_t)row * FF + c0 + i * 4];
    f4 v2 = *(const f4*)&o2[(size_t)row * FF + c0 + i * 4];
    f4 v3 = *(const f4*)&o3[(size_t)row * FF + c0 + i * 4];
    f4 o;
#pragma unroll
    for (int e = 0; e < 4; ++e) {
      float x = (v0[e] + v1[e] + v2[e] + v3[e]) * linv;
      o[e] = (x > 0.f) ? x : (__expf(x) - 1.f);
    }
    *(f4*)&out[(size_t)row * FF + c0 + i * 4] = o;
  }
}

extern "C" void kernel_launch(void* const* d_in, const int* in_sizes, int n_in,
                              void* d_out, int out_size, void* d_ws, size_t ws_size,
                              hipStream_t stream) {
  const float* h   = (const float*)d_in[0];
  const int*   adj = (const int*)d_in[1];
  const float* W   = (const float*)d_in[2];
  const float* a   = (const float*)d_in[3];
  float* out = (float*)d_out;

  char* ws = (char*)d_ws;
  _Float16* wfrag = (_Float16*)ws;                                 // 4 MB
  float*    o1    = (float*)(ws + (4u << 20));                     // 8 MB (kq=1)
  float*    o2    = (float*)(ws + (12u << 20));                    // 8 MB (kq=2)
  float*    o3    = (float*)(ws + (20u << 20));                    // 8 MB (kq=3)
  float*    lbuf  = (float*)(ws + (28u << 20));                    // 128 KB (4 x 8192)
  unsigned* s2me  = (unsigned*)(ws + (28u << 20) + 131072);        // 4 B (+60 pad)
  float*    s1    = (float*)(ws + (28u << 20) + 131072 + 64);      // 32 KB
  _Float16* s2h   = (_Float16*)(ws + (28u << 20) + 131072 + 64 + 32768); // 16 KB

  hipMemsetAsync(s2me, 0, 4, stream);   // fenc-domain -inf
  k_wh<<<512, 256, 0, stream>>>(h, W, a, wfrag, s1, s2h, s2me);
  k_gat<<<1024, 512, 0, stream>>>(adj, wfrag, s1, s2h, s2me, out, o1, o2, o3, lbuf);
  k_fin<<<512, 256, 0, stream>>>(out, o1, o2, o3, lbuf);
}

// Round 9
// 423.644 us; speedup vs baseline: 1.9019x; 1.0110x over previous
//
#include <hip/hip_runtime.h>

#define NN 8192
#define FF 256
#define PST 136   // P LDS row stride in halves (128 + 8 pad, 16B-aligned)

typedef _Float16 h8 __attribute__((ext_vector_type(8)));
typedef _Float16 h4 __attribute__((ext_vector_type(4)));
typedef float    f4 __attribute__((ext_vector_type(4)));
typedef int      i4v __attribute__((ext_vector_type(4)));

// monotone float<->uint encoding for atomicMax on fp32
__device__ __forceinline__ unsigned fenc(float x) {
  unsigned u = __float_as_uint(x);
  return (u & 0x80000000u) ? ~u : (u | 0x80000000u);
}
__device__ __forceinline__ float fdec(unsigned e) {
  unsigned u = (e & 0x80000000u) ? (e ^ 0x80000000u) : ~e;
  return __uint_as_float(u);
}

// lgkm-only barrier (CK block_sync_lds pattern): publishes LDS writes without
// draining vmem (plain __syncthreads emits s_waitcnt vmcnt(0) -> kills the
// adj prefetch pipeline).
__device__ __forceinline__ void sync_lds() {
  __builtin_amdgcn_s_waitcnt(0xc07f);   // lgkmcnt(0), vmcnt/expcnt ignored
  __builtin_amdgcn_s_barrier();
}

// ---------------- Kernel 1: Wh = h@W (fp32 vector), s1, s2(f16), wfrag -------
// grid 512 x 256 thr. Block = 16 rows of h = half of k-tile (blockIdx>>1).
// wfrag[(kt*16+n)*512 + lane*8 + j] = Wh[kt*32 + (lane>>4)*8 + j][n*16 + (lane&15)]
// R4 fix: s2max via per-block LDS reduction + ONE atomicMax per block
// (was 8192 single-address device atomics -> ~90 us serialization tail).
__global__ __launch_bounds__(256) void k_wh(
    const float* __restrict__ h, const float* __restrict__ W,
    const float* __restrict__ a, _Float16* __restrict__ wfrag,
    float* __restrict__ s1, _Float16* __restrict__ s2h,
    unsigned* __restrict__ s2maxe) {
  __shared__ float hs[16 * 256];        // 16 KB
  __shared__ _Float16 whs[16 * 264];    // 8.25 KB
  __shared__ unsigned bm[4];            // per-wave p2-max (fenc domain)
  const int t = threadIdx.x;
  const int r0 = blockIdx.x * 16;
#pragma unroll
  for (int i = 0; i < 4; ++i) {
    int idx = i * 1024 + t * 4;
    *(f4*)&hs[idx] = *(const f4*)&h[(size_t)r0 * 256 + idx];
  }
  __syncthreads();
  const int lane = t & 63;
  const int wv = t >> 6;        // 0..3
  const int rg = wv * 4;
  const int c4 = lane * 4;
  float acc[4][4];
#pragma unroll
  for (int i = 0; i < 4; ++i)
#pragma unroll
    for (int k = 0; k < 4; ++k) acc[i][k] = 0.f;
  f4 w[8];
#pragma unroll
  for (int i = 0; i < 8; ++i) w[i] = *(const f4*)&W[i * 256 + c4];
  for (int f = 0; f < 256; f += 8) {
    f4 nw[8];
    if (f < 248) {
#pragma unroll
      for (int i = 0; i < 8; ++i) nw[i] = *(const f4*)&W[(f + 8 + i) * 256 + c4];
    }
#pragma unroll
    for (int i = 0; i < 4; ++i) {
      f4 h0 = *(const f4*)&hs[(rg + i) * 256 + f];
      f4 h1 = *(const f4*)&hs[(rg + i) * 256 + f + 4];
#pragma unroll
      for (int k = 0; k < 4; ++k)
        acc[i][k] += h0[0]*w[0][k] + h0[1]*w[1][k] + h0[2]*w[2][k] + h0[3]*w[3][k]
                   + h1[0]*w[4][k] + h1[1]*w[5][k] + h1[2]*w[6][k] + h1[3]*w[7][k];
    }
    if (f < 248) {
#pragma unroll
      for (int i = 0; i < 8; ++i) w[i] = nw[i];
    }
  }
  float a1v[4], a2v[4];
#pragma unroll
  for (int k = 0; k < 4; ++k) { a1v[k] = a[c4 + k]; a2v[k] = a[256 + c4 + k]; }
  unsigned wmax = 0u;   // fenc domain: 0 < fenc(x) for all finite x
#pragma unroll
  for (int i = 0; i < 4; ++i) {
    h4 hh;
    float p1 = 0.f, p2 = 0.f;
#pragma unroll
    for (int k = 0; k < 4; ++k) {
      hh[k] = (_Float16)acc[i][k];
      p1 += acc[i][k] * a1v[k];
      p2 += acc[i][k] * a2v[k];
    }
    *(h4*)&whs[(rg + i) * 264 + c4] = hh;
#pragma unroll
    for (int off = 32; off; off >>= 1) {
      p1 += __shfl_xor(p1, off);
      p2 += __shfl_xor(p2, off);
    }
    if (lane == 0) {
      const int r = r0 + rg + i;
      s1[r] = p1;
      s2h[r] = (_Float16)p2;
      const unsigned e = fenc(p2);
      wmax = (e > wmax) ? e : wmax;
    }
  }
  if (lane == 0) bm[wv] = wmax;
  __syncthreads();
  if (t == 0) {
    unsigned m01 = (bm[0] > bm[1]) ? bm[0] : bm[1];
    unsigned m23 = (bm[2] > bm[3]) ? bm[2] : bm[3];
    atomicMax(s2maxe, (m01 > m23) ? m01 : m23);   // 1 atomic per block (512 total)
  }
  {
    const int kt = blockIdx.x >> 1;
    const int hb = blockIdx.x & 1;
    const int lp = hb * 32 + (t & 31);
    const int kb = ((t & 31) >> 4) * 8;
    const int m16e = t & 15;
#pragma unroll
    for (int p = 0; p < 2; ++p) {
      const int n = (t >> 5) + p * 8;
      h8 v;
#pragma unroll
      for (int j = 0; j < 8; ++j) v[j] = whs[(kb + j) * 264 + n * 16 + m16e];
      *(h8*)&wfrag[(((size_t)kt * 16 + n) << 9) + lp * 8] = v;
    }
  }
}

// ---------------- Kernel 2: fused attention ----------------------------------
// R7 post-mortem: occupancy axis exhausted (R6 spill, R7 +10us from doubled
// barrier count). R8: REVERT to R5 geometry (64-row, grid 512, LB(512,4),
// 2 blocks/CU, 16 periods) + SOFTWARE-PIPELINE the period: scores(p+1) are
// computed in the SAME region as MFMA(p) (independent: different P buffer,
// VALU vs MFMA pipes) so the compiler can interleave them. adj prefetch goes
// 2-deep (issue p+2, consume p+1). One lgkm-barrier per period, same as R5.
// FP op order per element is IDENTICAL to R5 -> absmax must be bit-identical.
// [R8 bench was an infra failure (container), resubmitted unchanged in R9.]
__global__ __launch_bounds__(512, 4) void k_gat(
    const int* __restrict__ adj, const _Float16* __restrict__ wfrag,
    const float* __restrict__ s1g, const _Float16* __restrict__ s2h,
    const unsigned* __restrict__ s2maxe,
    float* __restrict__ o0, float* __restrict__ o1,
    float* __restrict__ o2, float* __restrict__ o3,
    float* __restrict__ lbuf) {
  __shared__ _Float16 P[2][64 * PST];   // 34 KB
  __shared__ _Float16 s2l[2048];        // 4 KB
  const int t = threadIdx.x;
  const int lane = t & 63;
  const int w = t >> 6;          // 0..7: score rows {8w+q, 8w+q+4}; cols [32w,32w+32)
  const int q = lane >> 4;       // 0..3
  const int m16 = lane & 15;
  const int rt = (int)blockIdx.x >> 2;
  const int kq = (int)blockIdx.x & 3;
  const int r0 = rt * 64;

  if (t < 256) ((h8*)s2l)[t] = ((const h8*)(s2h + kq * 2048))[t];  // kq-quarter s2

  const int srA = 8 * w + q;                 // lane's two score rows (local)
  const int srB = srA + 4;
  const float s2m = fdec(*s2maxe);
  const float s1A = s1g[r0 + srA];
  const float s1B = s1g[r0 + srB];
  const float uA0 = s1A + s2m, uB0 = s1B + s2m;
  const float miA = fmaxf(uA0, 0.2f * uA0);  // >= leaky(s1+s2[j]) for all j
  const float miB = fmaxf(uB0, 0.2f * uB0);
  const float sAmi = s1A - miA, sBmi = s1B - miB;

  f4 acc[4][2];
#pragma unroll
  for (int m = 0; m < 4; ++m)
#pragma unroll
    for (int n = 0; n < 2; ++n)
#pragma unroll
      for (int e = 0; e < 4; ++e) acc[m][n][e] = 0.f;
  float lsA = 0.f, lsB = 0.f;

  const int* adjA = adj + (size_t)(r0 + srA) * NN + kq * 2048 + m16 * 8;
  const int* adjB = adj + (size_t)(r0 + srB) * NN + kq * 2048 + m16 * 8;
  __syncthreads();   // s2l ready (once; full drain harmless here)

  // prologue: gen0 (p=0) + gen1 (p=1) adj issues, scores(0) -> P[0]
  i4v g0a0 = *(const i4v*)(adjA);
  i4v g0a1 = *(const i4v*)(adjA + 4);
  i4v g0b0 = *(const i4v*)(adjB);
  i4v g0b1 = *(const i4v*)(adjB + 4);
  i4v cNa0 = *(const i4v*)(adjA + 128);
  i4v cNa1 = *(const i4v*)(adjA + 132);
  i4v cNb0 = *(const i4v*)(adjB + 128);
  i4v cNb1 = *(const i4v*)(adjB + 132);
  {
    const h8 s2c = *(const h8*)&s2l[m16 * 8];
    h8 pA, pB;
#pragma unroll
    for (int j = 0; j < 8; ++j) {
      const float s2v = (float)s2c[j];
      const int mA = (j < 4) ? g0a0[j] : g0a1[j - 4];
      const int mB = (j < 4) ? g0b0[j] : g0b1[j - 4];
      const float uA = s1A + s2v;
      const float uB = s1B + s2v;
      const float argA = sAmi + s2v - 0.8f * fminf(uA, 0.f);
      const float argB = sBmi + s2v - 0.8f * fminf(uB, 0.f);
      const float pvA = (mA > 0) ? __expf(argA) : 0.f;
      const float pvB = (mB > 0) ? __expf(argB) : 0.f;
      lsA += pvA; pA[j] = (_Float16)pvA;
      lsB += pvB; pB[j] = (_Float16)pvB;
    }
    _Float16* Pw = &P[0][0];
    *(h8*)&Pw[srA * PST + m16 * 8] = pA;
    *(h8*)&Pw[srB * PST + m16 * 8] = pB;
  }
  sync_lds();

  for (int p = 0; p < 16; ++p) {
    // (1) B-frags for this period (oldest vmem: MFMA waits only on these)
    const _Float16* wfb =
        wfrag + ((((size_t)(kq * 64 + p * 4)) * 16 + 2 * w) << 9) + lane * 8;
    h8 bb[8];
#pragma unroll
    for (int ks = 0; ks < 4; ++ks) {
      bb[2 * ks]     = *(const h8*)(wfb + ks * 8192);
      bb[2 * ks + 1] = *(const h8*)(wfb + ks * 8192 + 512);
    }
    // (2) adj issue for p+2 (consumed by scores in period p+1)
    i4v fa0 = cNa0, fa1 = cNa1, fb0 = cNb0, fb1 = cNb1;
    if (p < 14) {
      fa0 = *(const i4v*)(adjA + (p + 2) * 128);
      fa1 = *(const i4v*)(adjA + (p + 2) * 128 + 4);
      fb0 = *(const i4v*)(adjB + (p + 2) * 128);
      fb1 = *(const i4v*)(adjB + (p + 2) * 128 + 4);
    }
    // (3) scores(p+1) -> P[(p+1)&1]: independent of MFMA(p) below; the
    // compiler can interleave this VALU work with the MFMA pipe.
    if (p < 15) {
      const h8 s2c = *(const h8*)&s2l[(p + 1) * 128 + m16 * 8];
      h8 pA, pB;
#pragma unroll
      for (int j = 0; j < 8; ++j) {
        const float s2v = (float)s2c[j];
        const int mA = (j < 4) ? cNa0[j] : cNa1[j - 4];
        const int mB = (j < 4) ? cNb0[j] : cNb1[j - 4];
        const float uA = s1A + s2v;
        const float uB = s1B + s2v;
        const float argA = sAmi + s2v - 0.8f * fminf(uA, 0.f);
        const float argB = sBmi + s2v - 0.8f * fminf(uB, 0.f);
        const float pvA = (mA > 0) ? __expf(argA) : 0.f;
        const float pvB = (mB > 0) ? __expf(argB) : 0.f;
        lsA += pvA; pA[j] = (_Float16)pvA;
        lsB += pvB; pB[j] = (_Float16)pvB;
      }
      _Float16* Pw = &P[(p + 1) & 1][0];
      *(h8*)&Pw[srA * PST + m16 * 8] = pA;
      *(h8*)&Pw[srB * PST + m16 * 8] = pB;
    }
    // (4) MFMA(p): A from P[p&1], B from regs
    _Float16* Pb = &P[p & 1][0];
#pragma unroll
    for (int ks = 0; ks < 4; ++ks) {
      const h8 A0 = *(const h8*)&Pb[(     m16) * PST + ks * 32 + q * 8];
      const h8 A1 = *(const h8*)&Pb[(16 + m16) * PST + ks * 32 + q * 8];
      const h8 A2 = *(const h8*)&Pb[(32 + m16) * PST + ks * 32 + q * 8];
      const h8 A3 = *(const h8*)&Pb[(48 + m16) * PST + ks * 32 + q * 8];
      acc[0][0] = __builtin_amdgcn_mfma_f32_16x16x32_f16(A0, bb[2*ks],   acc[0][0], 0, 0, 0);
      acc[0][1] = __builtin_amdgcn_mfma_f32_16x16x32_f16(A0, bb[2*ks+1], acc[0][1], 0, 0, 0);
      acc[1][0] = __builtin_amdgcn_mfma_f32_16x16x32_f16(A1, bb[2*ks],   acc[1][0], 0, 0, 0);
      acc[1][1] = __builtin_amdgcn_mfma_f32_16x16x32_f16(A1, bb[2*ks+1], acc[1][1], 0, 0, 0);
      acc[2][0] = __builtin_amdgcn_mfma_f32_16x16x32_f16(A2, bb[2*ks],   acc[2][0], 0, 0, 0);
      acc[2][1] = __builtin_amdgcn_mfma_f32_16x16x32_f16(A2, bb[2*ks+1], acc[2][1], 0, 0, 0);
      acc[3][0] = __builtin_amdgcn_mfma_f32_16x16x32_f16(A3, bb[2*ks],   acc[3][0], 0, 0, 0);
      acc[3][1] = __builtin_amdgcn_mfma_f32_16x16x32_f16(A3, bb[2*ks+1], acc[3][1], 0, 0, 0);
    }
    // (5) one barrier per period: publishes P(p+1), protects P(p) reads
    sync_lds();
    cNa0 = fa0; cNa1 = fa1; cNb0 = fb0; cNb1 = fb1;
  }

  // partial softmax denominators: reduce over the 16 m16 lanes
  lsA += __shfl_xor(lsA, 1);
  lsA += __shfl_xor(lsA, 2);
  lsA += __shfl_xor(lsA, 4);
  lsA += __shfl_xor(lsA, 8);
  lsB += __shfl_xor(lsB, 1);
  lsB += __shfl_xor(lsB, 2);
  lsB += __shfl_xor(lsB, 4);
  lsB += __shfl_xor(lsB, 8);
  if (m16 == 0) {
    lbuf[kq * NN + r0 + srA] = lsA;
    lbuf[kq * NN + r0 + srB] = lsB;
  }

  // partial O: plain stores (each element written once per kq)
  float* ob = (kq == 0) ? o0 : (kq == 1) ? o1 : (kq == 2) ? o2 : o3;
#pragma unroll
  for (int m = 0; m < 4; ++m)
#pragma unroll
    for (int n = 0; n < 2; ++n)
#pragma unroll
      for (int v = 0; v < 4; ++v)
        ob[(size_t)(r0 + m * 16 + q * 4 + v) * FF + w * 32 + n * 16 + m16] =
            acc[m][n][v];
}

// ---------------- Kernel 3: combine quarters, normalize, elu -----------------
__global__ __launch_bounds__(256) void k_fin(
    float* __restrict__ out, const float* __restrict__ o1,
    const float* __restrict__ o2, const float* __restrict__ o3,
    const float* __restrict__ lbuf) {
  const int t = threadIdx.x;
  const int row = blockIdx.x * 16 + (t >> 4);
  const int c0 = (t & 15) * 16;
  const float linv = 1.0f / (lbuf[row] + lbuf[NN + row] +
                             lbuf[2 * NN + row] + lbuf[3 * NN + row]);
#pragma unroll
  for (int i = 0; i < 4; ++i) {
    f4 v0 = *(const f4*)&out[(size_t)row * FF + c0 + i * 4];
    f4 v1 = *(const f4*)&o1[(size_t)row * FF + c0 + i * 4];
    f4 v2 = *(const f4*)&o2[(size_t)row * FF + c0 + i * 4];
    f4 v3 = *(const f4*)&o3[(size_t)row * FF + c0 + i * 4];
    f4 o;
#pragma unroll
    for (int e = 0; e < 4; ++e) {
      float x = (v0[e] + v1[e] + v2[e] + v3[e]) * linv;
      o[e] = (x > 0.f) ? x : (__expf(x) - 1.f);
    }
    *(f4*)&out[(size_t)row * FF + c0 + i * 4] = o;
  }
}

extern "C" void kernel_launch(void* const* d_in, const int* in_sizes, int n_in,
                              void* d_out, int out_size, void* d_ws, size_t ws_size,
                              hipStream_t stream) {
  const float* h   = (const float*)d_in[0];
  const int*   adj = (const int*)d_in[1];
  const float* W   = (const float*)d_in[2];
  const float* a   = (const float*)d_in[3];
  float* out = (float*)d_out;

  char* ws = (char*)d_ws;
  _Float16* wfrag = (_Float16*)ws;                                 // 4 MB
  float*    o1    = (float*)(ws + (4u << 20));                     // 8 MB (kq=1)
  float*    o2    = (float*)(ws + (12u << 20));                    // 8 MB (kq=2)
  float*    o3    = (float*)(ws + (20u << 20));                    // 8 MB (kq=3)
  float*    lbuf  = (float*)(ws + (28u << 20));                    // 128 KB (4 x 8192)
  unsigned* s2me  = (unsigned*)(ws + (28u << 20) + 131072);        // 4 B (+60 pad)
  float*    s1    = (float*)(ws + (28u << 20) + 131072 + 64);      // 32 KB
  _Float16* s2h   = (_Float16*)(ws + (28u << 20) + 131072 + 64 + 32768); // 16 KB

  hipMemsetAsync(s2me, 0, 4, stream);   // fenc-domain -inf
  k_wh<<<512, 256, 0, stream>>>(h, W, a, wfrag, s1, s2h, s2me);
  k_gat<<<512, 512, 0, stream>>>(adj, wfrag, s1, s2h, s2me, out, o1, o2, o3, lbuf);
  k_fin<<<512, 256, 0, stream>>>(out, o1, o2, o3, lbuf);
}